// Round 6
// baseline (318.301 us; speedup 1.0000x reference)
//
#include <hip/hip_runtime.h>
#include <hip/hip_bf16.h>
#include <hip/hip_fp16.h>

typedef __attribute__((ext_vector_type(4))) float f32x4;
typedef __attribute__((ext_vector_type(8))) _Float16 f16x8;
typedef __attribute__((ext_vector_type(8))) unsigned short u16x8;

__device__ __forceinline__ unsigned short f2h(float f) {
    _Float16 h = (_Float16)f;
    return __builtin_bit_cast(unsigned short, h);
}

#define GLOAD_LDS16(gp, lp) __builtin_amdgcn_global_load_lds( \
    (const __attribute__((address_space(1))) void*)(gp), \
    (__attribute__((address_space(3))) void*)(lp), 16, 0, 0)
#define PRIO1() __builtin_amdgcn_s_setprio(1)
#define PRIO0() __builtin_amdgcn_s_setprio(0)

// ---------------- fp32 -> fp16 elementwise convert (vectorized) ----------------
__global__ void cvt_kernel(const float* __restrict__ in, ushort* __restrict__ out, int n4) {
    int stride = gridDim.x * blockDim.x;
    for (int i = blockIdx.x * blockDim.x + threadIdx.x; i < n4; i += stride) {
        float4 v = ((const float4*)in)[i];
        ushort4 o;
        o.x = f2h(v.x); o.y = f2h(v.y); o.z = f2h(v.z); o.w = f2h(v.w);
        ((ushort4*)out)[i] = o;
    }
}

// ---------------- merged transpose+convert for all 4 weights (grid.z picks) ----------------
__global__ void transpose_cvt4(const float* __restrict__ Wq, const float* __restrict__ Wo,
                               const float* __restrict__ Wk, const float* __restrict__ Wv,
                               ushort* __restrict__ WqT, ushort* __restrict__ WoT,
                               ushort* __restrict__ WkvT) {
    __shared__ float tile[32][33];
    const int z = blockIdx.z;
    const float* src; ushort* dst; int R;
    const int C = 640;
    if (z == 0)      { src = Wq; dst = WqT;  R = 640; }
    else if (z == 1) { src = Wo; dst = WoT;  R = 640; }
    else if (z == 2) { src = Wk; dst = WkvT; R = 768; }
    else             { src = Wv; dst = WkvT + (size_t)640 * 768; R = 768; }
    if (blockIdx.y * 32 >= (unsigned)R) return;
    int tx = threadIdx.x, ty = threadIdx.y;
    int c = blockIdx.x * 32 + tx;
    int r0 = blockIdx.y * 32;
#pragma unroll
    for (int i = ty; i < 32; i += 8) {
        int r = r0 + i;
        tile[i][tx] = (r < R && c < C) ? src[(size_t)r * C + c] : 0.f;
    }
    __syncthreads();
    int rr = r0 + tx;
    int c0 = blockIdx.x * 32;
#pragma unroll
    for (int i = ty; i < 32; i += 8) {
        int cc = c0 + i;
        if (cc < C && rr < R) dst[(size_t)cc * R + rr] = f2h(tile[tx][i]);
    }
}

// ---------------- 128x128 GEMM (for the tiny KV projection) ----------------
template<int OUT_F16, int HAS_BIAS>
__global__ __launch_bounds__(256) void gemm_bt(
    const ushort* __restrict__ A, const ushort* __restrict__ Bt,
    void* __restrict__ C, const float* __restrict__ bias,
    int M, int N, int K)
{
    __shared__ ushort As[128 * 64];
    __shared__ ushort Bs[128 * 64];
    const int tid = threadIdx.x;
    const int lane = tid & 63;
    const int w = tid >> 6;
    const int wr = (w >> 1) * 64, wc = (w & 1) * 64;
    const int m0 = blockIdx.x * 128, n0 = blockIdx.y * 128;
    const int l15 = lane & 15, lhi = lane >> 4;

    f32x4 acc[4][4] = {};

    for (int k0 = 0; k0 < K; k0 += 64) {
        __syncthreads();
#pragma unroll
        for (int i = 0; i < 4; ++i) {
            int c = i * 256 + tid;
            int m = m0 + (c >> 3);
            if (m > M - 1) m = M - 1;
            GLOAD_LDS16(A + (size_t)m * K + k0 + (c & 7) * 8, &As[c * 8]);
        }
#pragma unroll
        for (int i = 0; i < 4; ++i) {
            int c = i * 256 + tid;
            GLOAD_LDS16(Bt + (size_t)(n0 + (c >> 3)) * K + k0 + (c & 7) * 8, &Bs[c * 8]);
        }
        __syncthreads();
#pragma unroll
        for (int kk = 0; kk < 2; ++kk) {
            f16x8 af[4], bfr[4];
#pragma unroll
            for (int mi = 0; mi < 4; ++mi)
                af[mi] = *(const f16x8*)&As[(wr + mi * 16 + l15) * 64 + kk * 32 + lhi * 8];
#pragma unroll
            for (int ni = 0; ni < 4; ++ni)
                bfr[ni] = *(const f16x8*)&Bs[(wc + ni * 16 + l15) * 64 + kk * 32 + lhi * 8];
#pragma unroll
            for (int mi = 0; mi < 4; ++mi)
#pragma unroll
                for (int ni = 0; ni < 4; ++ni)
                    acc[mi][ni] = __builtin_amdgcn_mfma_f32_16x16x32_f16(
                        af[mi], bfr[ni], acc[mi][ni], 0, 0, 0);
        }
    }

#pragma unroll
    for (int mi = 0; mi < 4; ++mi)
#pragma unroll
        for (int ni = 0; ni < 4; ++ni)
#pragma unroll
            for (int r = 0; r < 4; ++r) {
                int row = m0 + wr + mi * 16 + lhi * 4 + r;
                int col = n0 + wc + ni * 16 + l15;
                if (row < M) {
                    float v = acc[mi][ni][r];
                    if (HAS_BIAS) v += bias[col];
                    if (OUT_F16) ((ushort*)C)[(size_t)row * N + col] = f2h(v);
                    else         ((float*)C)[(size_t)row * N + col] = v;
                }
            }
}

// ---------------- build V^T: Vt[b][h][d=80][s=96] = V[b][s][h*80+d], zero-pad s>=77 ----------------
__global__ void vtrans_kernel(const ushort* __restrict__ KVb, ushort* __restrict__ Vt) {
    int bh = blockIdx.x;        // b*8 + h
    int b = bh >> 3, h = bh & 7;
    for (int idx = threadIdx.x; idx < 80 * 96; idx += 256) {
        int d = idx / 96, s = idx % 96;
        ushort v = 0;
        if (s < 77) v = KVb[((size_t)b * 77 + s) * 1280 + 640 + h * 80 + d];
        Vt[(size_t)bh * 7680 + idx] = v;
    }
}

// ================= fused: tokens->Q-proj->attention->O-proj->out =================
// grid (64 tt, 8 b), 512 threads = 8 waves; wave w handles head w.
// LDS 80 KiB exactly:
//   token dbuf [64][64] f16 swz @ 0 / 4096 ushorts   (dead after Q-proj)
//   Q/P per-wave [64][80] @ w*5120                   (alias bufs; dead after PV)
//   ctxall [64][640] 16B-slot XOR swz @ 0            (alias everything)
// Phantom k-slots (d or s in 80..95) handled by zeroing the A-fragment at kk=2, lhi>=2.
// __launch_bounds__ calibration on this toolchain (R4/R5 A/B):
//   (512,4) -> VGPR cap 64 (spilled, bad) but 2 blocks/CU resident (occ 44%)
//   (512,2) -> VGPR 112 natural, but only 1 block/CU resident (occ 20%)
//   (512,3) -> this round's experiment: want >=12 waves/CU (2 blocks) with VGPR budget >=112.
__global__ __launch_bounds__(512, 3) void fused_attn(
    const float* __restrict__ tokens, const ushort* __restrict__ WqT,
    const ushort* __restrict__ KVb, const ushort* __restrict__ Vt_g,
    const ushort* __restrict__ WoT, const float* __restrict__ bo,
    float* __restrict__ out)
{
    __shared__ __align__(16) ushort lds[40960];   // 80 KiB
    const int tid = threadIdx.x;
    const int lane = tid & 63;
    const int w = tid >> 6;
    const int l15 = lane & 15, lhi = lane >> 4;
    const int tt = blockIdx.x, b = blockIdx.y;
    const size_t rowbase = (size_t)b * 4096 + (size_t)tt * 64;

    // staging indices: each thread stages one 8-f32 group per 64x64 chunk
    const int srow = tid >> 3;            // 0..63
    const int sc8  = tid & 7;             // slot 0..7
    const int sphys = sc8 ^ (srow & 7);   // swizzled slot

    // ---- prologue: stage tokens chunk 0 into bufA ----
    {
        const float4* sp = (const float4*)(tokens + (rowbase + srow) * 640 + sc8 * 8);
        float4 v0 = sp[0], v1 = sp[1];
        u16x8 o;
        o[0]=f2h(v0.x); o[1]=f2h(v0.y); o[2]=f2h(v0.z); o[3]=f2h(v0.w);
        o[4]=f2h(v1.x); o[5]=f2h(v1.y); o[6]=f2h(v1.z); o[7]=f2h(v1.w);
        *(u16x8*)&lds[srow * 64 + sphys * 8] = o;
    }
    const ushort* Wrow = WqT + (size_t)(w * 80) * 640;
    f16x8 BbE[10], BbO[10];
#pragma unroll
    for (int ni = 0; ni < 5; ++ni)
#pragma unroll
        for (int kk = 0; kk < 2; ++kk)
            BbE[ni*2+kk] = *(const f16x8*)(Wrow + (size_t)(ni*16 + l15) * 640 + kk*32 + lhi*8);
    __syncthreads();

    // ---- Q projection: qacc[4][5] = tokens_tile(64x640) @ Wq[:, w*80..+80] ----
    f32x4 qacc[4][5] = {};
#define QSTEP(BCUR, BNXT, KT, CURB, NXTB) do { \
    float4 s0_, s1_; \
    const int kt_ = (KT); \
    if (kt_ < 9) { \
        const float4* sp_ = (const float4*)(tokens + (rowbase + srow) * 640 + (kt_+1)*64 + sc8*8); \
        s0_ = sp_[0]; s1_ = sp_[1]; \
        _Pragma("unroll") for (int ni = 0; ni < 5; ++ni) \
        _Pragma("unroll") for (int kk = 0; kk < 2; ++kk) \
            (BNXT)[ni*2+kk] = *(const f16x8*)(Wrow + (size_t)(ni*16+l15)*640 + (kt_+1)*64 + kk*32 + lhi*8); \
    } \
    _Pragma("unroll") for (int kk = 0; kk < 2; ++kk) { \
        f16x8 af[4]; \
        _Pragma("unroll") for (int mi = 0; mi < 4; ++mi) { \
            int row_ = mi*16 + l15; \
            af[mi] = *(const f16x8*)&lds[(CURB) + row_*64 + (((kk*4 + lhi) ^ (row_ & 7)))*8]; \
        } \
        PRIO1(); \
        _Pragma("unroll") for (int mi = 0; mi < 4; ++mi) \
        _Pragma("unroll") for (int ni = 0; ni < 5; ++ni) \
            qacc[mi][ni] = __builtin_amdgcn_mfma_f32_16x16x32_f16(af[mi], (BCUR)[ni*2+kk], qacc[mi][ni], 0, 0, 0); \
        PRIO0(); \
    } \
    if (kt_ < 9) { \
        u16x8 o_; \
        o_[0]=f2h(s0_.x); o_[1]=f2h(s0_.y); o_[2]=f2h(s0_.z); o_[3]=f2h(s0_.w); \
        o_[4]=f2h(s1_.x); o_[5]=f2h(s1_.y); o_[6]=f2h(s1_.z); o_[7]=f2h(s1_.w); \
        *(u16x8*)&lds[(NXTB) + srow*64 + sphys*8] = o_; \
    } \
    __syncthreads(); \
} while (0)

    for (int kp = 0; kp < 5; ++kp) {
        QSTEP(BbE, BbO, 2*kp,     0,    4096);
        QSTEP(BbO, BbE, 2*kp + 1, 4096, 0);
    }
#undef QSTEP

    // ---- write Q f16 into per-wave [64][80] region (aliases token bufs, now dead) ----
    const int qoff = w * 5120;
#pragma unroll
    for (int mi = 0; mi < 4; ++mi)
#pragma unroll
        for (int ni = 0; ni < 5; ++ni)
#pragma unroll
            for (int r = 0; r < 4; ++r)
                lds[qoff + (mi*16 + lhi*4 + r)*80 + ni*16 + l15] = f2h(qacc[mi][ni][r]);
    __builtin_amdgcn_sched_barrier(0);

    const f16x8 zf = {};
    // ---- S = Q K^T (per-wave, K frags from L2, rows clamped for s>=77) ----
    f32x4 sa[4][5] = {};
    {
        f16x8 bk[15];
        const ushort* Kbase = KVb + (size_t)b * 77 * 1280 + w * 80;
#pragma unroll
        for (int ni = 0; ni < 5; ++ni) {
            int s = ni*16 + l15;
            int sr = s < 77 ? s : 76;
#pragma unroll
            for (int kk = 0; kk < 3; ++kk)
                bk[ni*3+kk] = *(const f16x8*)(Kbase + (size_t)sr * 1280 + kk*32 + lhi*8);
        }
#pragma unroll
        for (int kk = 0; kk < 3; ++kk) {
            f16x8 aq[4];
            const int kcol = (kk < 2) ? (kk*32 + lhi*8) : (64 + (lhi & 1)*8);
#pragma unroll
            for (int mi = 0; mi < 4; ++mi) {
                aq[mi] = *(const f16x8*)&lds[qoff + (mi*16 + l15)*80 + kcol];
                if (kk == 2 && lhi >= 2) aq[mi] = zf;   // phantom k-slots d=80..95
            }
            PRIO1();
#pragma unroll
            for (int mi = 0; mi < 4; ++mi)
#pragma unroll
                for (int ni = 0; ni < 5; ++ni)
                    sa[mi][ni] = __builtin_amdgcn_mfma_f32_16x16x32_f16(aq[mi], bk[ni*3+kk], sa[mi][ni], 0, 0, 0);
            PRIO0();
        }
    }
    __builtin_amdgcn_sched_barrier(0);

    // ---- softmax over s (77 valid), store P f16 into the same per-wave region ----
    const float sc = 0.11180339887498949f;   // 1/sqrt(80)
#pragma unroll
    for (int mi = 0; mi < 4; ++mi)
#pragma unroll
        for (int r = 0; r < 4; ++r) {
            float v0 = sa[mi][0][r]*sc, v1 = sa[mi][1][r]*sc, v2 = sa[mi][2][r]*sc,
                  v3 = sa[mi][3][r]*sc, v4 = sa[mi][4][r]*sc;
            bool ok4 = l15 < 13;             // col 64+l15 < 77
            float mx = fmaxf(fmaxf(v0, v1), fmaxf(v2, v3));
            if (ok4) mx = fmaxf(mx, v4);
#pragma unroll
            for (int off = 1; off < 16; off <<= 1) mx = fmaxf(mx, __shfl_xor(mx, off, 16));
            float p0 = __expf(v0-mx), p1 = __expf(v1-mx), p2 = __expf(v2-mx), p3 = __expf(v3-mx);
            float p4 = ok4 ? __expf(v4-mx) : 0.f;
            float sm = p0+p1+p2+p3+p4;
#pragma unroll
            for (int off = 1; off < 16; off <<= 1) sm += __shfl_xor(sm, off, 16);
            float inv = 1.f / sm;
            int row = mi*16 + lhi*4 + r;
            lds[qoff + row*80 + 0*16 + l15] = f2h(p0*inv);
            lds[qoff + row*80 + 1*16 + l15] = f2h(p1*inv);
            lds[qoff + row*80 + 2*16 + l15] = f2h(p2*inv);
            lds[qoff + row*80 + 3*16 + l15] = f2h(p3*inv);
            lds[qoff + row*80 + 4*16 + l15] = f2h(p4*inv);
        }
    __builtin_amdgcn_sched_barrier(0);

    // ---- O = P V (V^T frags from L2; Vt cols 77..95 are true zeros) ----
    f32x4 oa[4][5] = {};
    {
        f16x8 bv[15];
        const ushort* Vbase = Vt_g + (size_t)(b*8 + w) * 7680;
#pragma unroll
        for (int ni = 0; ni < 5; ++ni)
#pragma unroll
            for (int kk = 0; kk < 3; ++kk)
                bv[ni*3+kk] = *(const f16x8*)(Vbase + (size_t)(ni*16 + l15)*96 + kk*32 + lhi*8);
#pragma unroll
        for (int kk = 0; kk < 3; ++kk) {
            f16x8 ap[4];
            const int kcol = (kk < 2) ? (kk*32 + lhi*8) : (64 + (lhi & 1)*8);
#pragma unroll
            for (int mi = 0; mi < 4; ++mi) {
                ap[mi] = *(const f16x8*)&lds[qoff + (mi*16 + l15)*80 + kcol];
                if (kk == 2 && lhi >= 2) ap[mi] = zf;   // phantom s=80..95
            }
            PRIO1();
#pragma unroll
            for (int mi = 0; mi < 4; ++mi)
#pragma unroll
                for (int ni = 0; ni < 5; ++ni)
                    oa[mi][ni] = __builtin_amdgcn_mfma_f32_16x16x32_f16(ap[mi], bv[ni*3+kk], oa[mi][ni], 0, 0, 0);
            PRIO0();
        }
    }
    __syncthreads();   // all waves done with Q/P regions before ctxall overwrites

    // ---- ctxall[64][640], 16B-slot XOR swizzle, = concat of heads ----
#pragma unroll
    for (int mi = 0; mi < 4; ++mi)
#pragma unroll
        for (int ni = 0; ni < 5; ++ni)
#pragma unroll
            for (int r = 0; r < 4; ++r) {
                int row = mi*16 + lhi*4 + r;
                int col = w*80 + ni*16 + l15;
                int slot = col >> 3;
                int phys = (((slot & ~7) | ((slot ^ row) & 7)) << 3) | (col & 7);
                lds[row*640 + phys] = f2h(oa[mi][ni][r]);
            }
    __syncthreads();

    // ---- O projection: out = ctxall @ Wo[:, w*80..+80] + bo ----
    f32x4 cacc[4][5] = {};
    const ushort* Orow = WoT + (size_t)(w * 80) * 640;
#pragma unroll
    for (int ni = 0; ni < 5; ++ni)
#pragma unroll
        for (int kk = 0; kk < 2; ++kk)
            BbE[ni*2+kk] = *(const f16x8*)(Orow + (size_t)(ni*16 + l15)*640 + kk*32 + lhi*8);
#define OSTEP(BCUR, BNXT, KT) do { \
    const int kt_ = (KT); \
    if (kt_ < 9) { \
        _Pragma("unroll") for (int ni = 0; ni < 5; ++ni) \
        _Pragma("unroll") for (int kk = 0; kk < 2; ++kk) \
            (BNXT)[ni*2+kk] = *(const f16x8*)(Orow + (size_t)(ni*16+l15)*640 + (kt_+1)*64 + kk*32 + lhi*8); \
    } \
    _Pragma("unroll") for (int kk = 0; kk < 2; ++kk) { \
        f16x8 af[4]; \
        _Pragma("unroll") for (int mi = 0; mi < 4; ++mi) { \
            int row_ = mi*16 + l15; \
            af[mi] = *(const f16x8*)&lds[row_*640 + ((kt_*8 + ((kk*4 + lhi) ^ (row_ & 7))))*8]; \
        } \
        PRIO1(); \
        _Pragma("unroll") for (int mi = 0; mi < 4; ++mi) \
        _Pragma("unroll") for (int ni = 0; ni < 5; ++ni) \
            cacc[mi][ni] = __builtin_amdgcn_mfma_f32_16x16x32_f16(af[mi], (BCUR)[ni*2+kk], cacc[mi][ni], 0, 0, 0); \
        PRIO0(); \
    } \
} while (0)
    for (int kp = 0; kp < 5; ++kp) {
        OSTEP(BbE, BbO, 2*kp);
        OSTEP(BbO, BbE, 2*kp + 1);
    }
#undef OSTEP

    // ---- epilogue: f32 out + bias ----
#pragma unroll
    for (int ni = 0; ni < 5; ++ni) {
        int col = w*80 + ni*16 + l15;
        float bvl = bo[col];
#pragma unroll
        for (int mi = 0; mi < 4; ++mi)
#pragma unroll
            for (int r = 0; r < 4; ++r)
                out[(rowbase + mi*16 + lhi*4 + r) * 640 + col] = cacc[mi][ni][r] + bvl;
    }
}

extern "C" void kernel_launch(void* const* d_in, const int* in_sizes, int n_in,
                              void* d_out, int out_size, void* d_ws, size_t ws_size,
                              hipStream_t stream) {
    (void)in_sizes; (void)n_in; (void)out_size; (void)ws_size;
    const float* tokens  = (const float*)d_in[0];
    const float* context = (const float*)d_in[1];
    const float* Wq = (const float*)d_in[2];
    const float* Wk = (const float*)d_in[3];
    const float* Wv = (const float*)d_in[4];
    const float* Wo = (const float*)d_in[5];
    const float* bo = (const float*)d_in[6];
    float* out = (float*)d_out;

    ushort* ws   = (ushort*)d_ws;
    ushort* ctx16 = ws;                                   // 616*768
    ushort* WqT  = ctx16 + (size_t)616 * 768;             // 640*640
    ushort* WoT  = WqT  + (size_t)640 * 640;              // 640*640
    ushort* WkvT = WoT  + (size_t)640 * 640;              // 1280*768
    ushort* KVb  = WkvT + (size_t)1280 * 768;             // 616*1280
    ushort* Vt_g = KVb  + (size_t)616 * 1280;             // 64*80*96

    cvt_kernel<<<462, 256, 0, stream>>>(context, ctx16, 616 * 768 / 4);
    transpose_cvt4<<<dim3(20, 24, 4), dim3(32, 8), 0, stream>>>(Wq, Wo, Wk, Wv, WqT, WoT, WkvT);
    gemm_bt<1, 0><<<dim3(5, 10), 256, 0, stream>>>(ctx16, WkvT, KVb, nullptr, 616, 1280, 768);
    vtrans_kernel<<<64, 256, 0, stream>>>(KVb, Vt_g);
    fused_attn<<<dim3(64, 8), 512, 0, stream>>>(tokens, WqT, KVb, Vt_g, WoT, bo, out);
}

// Round 7
// 260.057 us; speedup vs baseline: 1.2240x; 1.2240x over previous
//
#include <hip/hip_runtime.h>
#include <hip/hip_bf16.h>
#include <hip/hip_fp16.h>

typedef __attribute__((ext_vector_type(4))) float f32x4;
typedef __attribute__((ext_vector_type(8))) _Float16 f16x8;
typedef __attribute__((ext_vector_type(8))) unsigned short u16x8;

__device__ __forceinline__ unsigned short f2h(float f) {
    _Float16 h = (_Float16)f;
    return __builtin_bit_cast(unsigned short, h);
}

#define GLOAD_LDS16(gp, lp) __builtin_amdgcn_global_load_lds( \
    (const __attribute__((address_space(1))) void*)(gp), \
    (__attribute__((address_space(3))) void*)(lp), 16, 0, 0)
#define PRIO1() __builtin_amdgcn_s_setprio(1)
#define PRIO0() __builtin_amdgcn_s_setprio(0)

// ---------------- fp32 -> fp16 elementwise convert (vectorized) ----------------
__global__ void cvt_kernel(const float* __restrict__ in, ushort* __restrict__ out, int n4) {
    int stride = gridDim.x * blockDim.x;
    for (int i = blockIdx.x * blockDim.x + threadIdx.x; i < n4; i += stride) {
        float4 v = ((const float4*)in)[i];
        ushort4 o;
        o.x = f2h(v.x); o.y = f2h(v.y); o.z = f2h(v.z); o.w = f2h(v.w);
        ((ushort4*)out)[i] = o;
    }
}

// ---------------- merged transpose+convert for all 4 weights (grid.z picks) ----------------
__global__ void transpose_cvt4(const float* __restrict__ Wq, const float* __restrict__ Wo,
                               const float* __restrict__ Wk, const float* __restrict__ Wv,
                               ushort* __restrict__ WqT, ushort* __restrict__ WoT,
                               ushort* __restrict__ WkvT) {
    __shared__ float tile[32][33];
    const int z = blockIdx.z;
    const float* src; ushort* dst; int R;
    const int C = 640;
    if (z == 0)      { src = Wq; dst = WqT;  R = 640; }
    else if (z == 1) { src = Wo; dst = WoT;  R = 640; }
    else if (z == 2) { src = Wk; dst = WkvT; R = 768; }
    else             { src = Wv; dst = WkvT + (size_t)640 * 768; R = 768; }
    if (blockIdx.y * 32 >= (unsigned)R) return;
    int tx = threadIdx.x, ty = threadIdx.y;
    int c = blockIdx.x * 32 + tx;
    int r0 = blockIdx.y * 32;
#pragma unroll
    for (int i = ty; i < 32; i += 8) {
        int r = r0 + i;
        tile[i][tx] = (r < R && c < C) ? src[(size_t)r * C + c] : 0.f;
    }
    __syncthreads();
    int rr = r0 + tx;
    int c0 = blockIdx.x * 32;
#pragma unroll
    for (int i = ty; i < 32; i += 8) {
        int cc = c0 + i;
        if (cc < C && rr < R) dst[(size_t)cc * R + rr] = f2h(tile[tx][i]);
    }
}

// ---------------- 128x128 GEMM (for the tiny KV projection) ----------------
template<int OUT_F16, int HAS_BIAS>
__global__ __launch_bounds__(256) void gemm_bt(
    const ushort* __restrict__ A, const ushort* __restrict__ Bt,
    void* __restrict__ C, const float* __restrict__ bias,
    int M, int N, int K)
{
    __shared__ ushort As[128 * 64];
    __shared__ ushort Bs[128 * 64];
    const int tid = threadIdx.x;
    const int lane = tid & 63;
    const int w = tid >> 6;
    const int wr = (w >> 1) * 64, wc = (w & 1) * 64;
    const int m0 = blockIdx.x * 128, n0 = blockIdx.y * 128;
    const int l15 = lane & 15, lhi = lane >> 4;

    f32x4 acc[4][4] = {};

    for (int k0 = 0; k0 < K; k0 += 64) {
        __syncthreads();
#pragma unroll
        for (int i = 0; i < 4; ++i) {
            int c = i * 256 + tid;
            int m = m0 + (c >> 3);
            if (m > M - 1) m = M - 1;
            GLOAD_LDS16(A + (size_t)m * K + k0 + (c & 7) * 8, &As[c * 8]);
        }
#pragma unroll
        for (int i = 0; i < 4; ++i) {
            int c = i * 256 + tid;
            GLOAD_LDS16(Bt + (size_t)(n0 + (c >> 3)) * K + k0 + (c & 7) * 8, &Bs[c * 8]);
        }
        __syncthreads();
#pragma unroll
        for (int kk = 0; kk < 2; ++kk) {
            f16x8 af[4], bfr[4];
#pragma unroll
            for (int mi = 0; mi < 4; ++mi)
                af[mi] = *(const f16x8*)&As[(wr + mi * 16 + l15) * 64 + kk * 32 + lhi * 8];
#pragma unroll
            for (int ni = 0; ni < 4; ++ni)
                bfr[ni] = *(const f16x8*)&Bs[(wc + ni * 16 + l15) * 64 + kk * 32 + lhi * 8];
#pragma unroll
            for (int mi = 0; mi < 4; ++mi)
#pragma unroll
                for (int ni = 0; ni < 4; ++ni)
                    acc[mi][ni] = __builtin_amdgcn_mfma_f32_16x16x32_f16(
                        af[mi], bfr[ni], acc[mi][ni], 0, 0, 0);
        }
    }

#pragma unroll
    for (int mi = 0; mi < 4; ++mi)
#pragma unroll
        for (int ni = 0; ni < 4; ++ni)
#pragma unroll
            for (int r = 0; r < 4; ++r) {
                int row = m0 + wr + mi * 16 + lhi * 4 + r;
                int col = n0 + wc + ni * 16 + l15;
                if (row < M) {
                    float v = acc[mi][ni][r];
                    if (HAS_BIAS) v += bias[col];
                    if (OUT_F16) ((ushort*)C)[(size_t)row * N + col] = f2h(v);
                    else         ((float*)C)[(size_t)row * N + col] = v;
                }
            }
}

// ---------------- build V^T: Vt[b][h][d=80][s=96] = V[b][s][h*80+d], zero-pad s>=77 ----------------
__global__ void vtrans_kernel(const ushort* __restrict__ KVb, ushort* __restrict__ Vt) {
    int bh = blockIdx.x;        // b*8 + h
    int b = bh >> 3, h = bh & 7;
    for (int idx = threadIdx.x; idx < 80 * 96; idx += 256) {
        int d = idx / 96, s = idx % 96;
        ushort v = 0;
        if (s < 77) v = KVb[((size_t)b * 77 + s) * 1280 + 640 + h * 80 + d];
        Vt[(size_t)bh * 7680 + idx] = v;
    }
}

// ================= fused: tokens->Q-proj->attention->O-proj->out =================
// grid (128 tt, 8 b), 512 threads = 8 waves; wave w handles head w; 32 T-rows/block.
// LDS 44 KiB:
//   token dbuf [32][64] f16 swz @ 0 / 2048 ushorts       (dead after Q-proj)
//   Q/P per-wave [32][88] @ w*2816 ushorts               (alias bufs; dead after PV)
//   ctxall [32][640] 16B-slot XOR swz @ 0                (alias everything)
// [88] stride: 16B-aligned rows, 44-dword bank stride -> 2-way (free) LDS access.
// Phantom k-slots (d or s in 80..95): zero A-fragment at kk=2, lhi>=2.
// __launch_bounds__ 2nd arg calibration (R4/R5/R6): blocks-per-CU semantics;
//   VGPR caps 4->64 (spills), 3->84 (spills), 2->128 (natural ~112, clean). Keep 2.
__global__ __launch_bounds__(512, 2) void fused_attn(
    const float* __restrict__ tokens, const ushort* __restrict__ WqT,
    const ushort* __restrict__ KVb, const ushort* __restrict__ Vt_g,
    const ushort* __restrict__ WoT, const float* __restrict__ bo,
    float* __restrict__ out)
{
    __shared__ __align__(16) ushort lds[22528];   // 44 KiB
    const int tid = threadIdx.x;
    const int lane = tid & 63;
    const int w = tid >> 6;
    const int l15 = lane & 15, lhi = lane >> 4;
    const int tt = blockIdx.x, b = blockIdx.y;
    const size_t rowbase = (size_t)b * 4096 + (size_t)tt * 32;

    // staging: threads 0..255 each stage one u16x8 (8 f32 -> 8 f16) per 32x64 chunk
    const int srow = (tid & 255) >> 3;    // 0..31
    const int sc8  = tid & 7;             // slot 0..7
    const int sphys = sc8 ^ (srow & 7);   // swizzled 16B slot
    const bool stager = tid < 256;

    // ---- prologue: stage tokens chunk 0 into bufA ----
    if (stager) {
        const float4* sp = (const float4*)(tokens + (rowbase + srow) * 640 + sc8 * 8);
        float4 v0 = sp[0], v1 = sp[1];
        u16x8 o;
        o[0]=f2h(v0.x); o[1]=f2h(v0.y); o[2]=f2h(v0.z); o[3]=f2h(v0.w);
        o[4]=f2h(v1.x); o[5]=f2h(v1.y); o[6]=f2h(v1.z); o[7]=f2h(v1.w);
        *(u16x8*)&lds[srow * 64 + sphys * 8] = o;
    }
    const ushort* Wrow = WqT + (size_t)(w * 80) * 640;
    f16x8 BbE[10], BbO[10];
#pragma unroll
    for (int ni = 0; ni < 5; ++ni)
#pragma unroll
        for (int kk = 0; kk < 2; ++kk)
            BbE[ni*2+kk] = *(const f16x8*)(Wrow + (size_t)(ni*16 + l15) * 640 + kk*32 + lhi*8);
    __syncthreads();

    // ---- Q projection: qacc[2][5] = tokens_tile(32x640) @ Wq[:, w*80..+80] ----
    f32x4 qacc[2][5] = {};
#define QSTEP(BCUR, BNXT, KT, CURB, NXTB) do { \
    float4 s0_, s1_; \
    const int kt_ = (KT); \
    if (kt_ < 9) { \
        if (stager) { \
            const float4* sp_ = (const float4*)(tokens + (rowbase + srow) * 640 + (kt_+1)*64 + sc8*8); \
            s0_ = sp_[0]; s1_ = sp_[1]; \
        } \
        _Pragma("unroll") for (int ni = 0; ni < 5; ++ni) \
        _Pragma("unroll") for (int kk = 0; kk < 2; ++kk) \
            (BNXT)[ni*2+kk] = *(const f16x8*)(Wrow + (size_t)(ni*16+l15)*640 + (kt_+1)*64 + kk*32 + lhi*8); \
    } \
    _Pragma("unroll") for (int kk = 0; kk < 2; ++kk) { \
        f16x8 af[2]; \
        _Pragma("unroll") for (int mi = 0; mi < 2; ++mi) { \
            int row_ = mi*16 + l15; \
            af[mi] = *(const f16x8*)&lds[(CURB) + row_*64 + (((kk*4 + lhi) ^ (row_ & 7)))*8]; \
        } \
        PRIO1(); \
        _Pragma("unroll") for (int mi = 0; mi < 2; ++mi) \
        _Pragma("unroll") for (int ni = 0; ni < 5; ++ni) \
            qacc[mi][ni] = __builtin_amdgcn_mfma_f32_16x16x32_f16(af[mi], (BCUR)[ni*2+kk], qacc[mi][ni], 0, 0, 0); \
        PRIO0(); \
    } \
    if (kt_ < 9 && stager) { \
        u16x8 o_; \
        o_[0]=f2h(s0_.x); o_[1]=f2h(s0_.y); o_[2]=f2h(s0_.z); o_[3]=f2h(s0_.w); \
        o_[4]=f2h(s1_.x); o_[5]=f2h(s1_.y); o_[6]=f2h(s1_.z); o_[7]=f2h(s1_.w); \
        *(u16x8*)&lds[(NXTB) + srow*64 + sphys*8] = o_; \
    } \
    __syncthreads(); \
} while (0)

    for (int kp = 0; kp < 5; ++kp) {
        QSTEP(BbE, BbO, 2*kp,     0,    2048);
        QSTEP(BbO, BbE, 2*kp + 1, 2048, 0);
    }
#undef QSTEP

    // ---- write Q f16 into per-wave [32][88] region (aliases token bufs, now dead) ----
    const int qoff = w * 2816;
#pragma unroll
    for (int mi = 0; mi < 2; ++mi)
#pragma unroll
        for (int ni = 0; ni < 5; ++ni)
#pragma unroll
            for (int r = 0; r < 4; ++r)
                lds[qoff + (mi*16 + lhi*4 + r)*88 + ni*16 + l15] = f2h(qacc[mi][ni][r]);
    __builtin_amdgcn_sched_barrier(0);

    const f16x8 zf = {};
    // ---- S = Q K^T (per-wave, K frags from L2, rows clamped for s>=77) ----
    f32x4 sa[2][5] = {};
    {
        f16x8 bk[15];
        const ushort* Kbase = KVb + (size_t)b * 77 * 1280 + w * 80;
#pragma unroll
        for (int ni = 0; ni < 5; ++ni) {
            int s = ni*16 + l15;
            int sr = s < 77 ? s : 76;
#pragma unroll
            for (int kk = 0; kk < 3; ++kk)
                bk[ni*3+kk] = *(const f16x8*)(Kbase + (size_t)sr * 1280 + kk*32 + lhi*8);
        }
#pragma unroll
        for (int kk = 0; kk < 3; ++kk) {
            f16x8 aq[2];
            const int kcol = (kk < 2) ? (kk*32 + lhi*8) : (64 + (lhi & 1)*8);
#pragma unroll
            for (int mi = 0; mi < 2; ++mi) {
                aq[mi] = *(const f16x8*)&lds[qoff + (mi*16 + l15)*88 + kcol];
                if (kk == 2 && lhi >= 2) aq[mi] = zf;   // phantom k-slots d=80..95
            }
            PRIO1();
#pragma unroll
            for (int mi = 0; mi < 2; ++mi)
#pragma unroll
                for (int ni = 0; ni < 5; ++ni)
                    sa[mi][ni] = __builtin_amdgcn_mfma_f32_16x16x32_f16(aq[mi], bk[ni*3+kk], sa[mi][ni], 0, 0, 0);
            PRIO0();
        }
    }
    __builtin_amdgcn_sched_barrier(0);

    // ---- softmax over s (77 valid), store P f16 into the same per-wave region ----
    const float sc = 0.11180339887498949f;   // 1/sqrt(80)
#pragma unroll
    for (int mi = 0; mi < 2; ++mi)
#pragma unroll
        for (int r = 0; r < 4; ++r) {
            float v0 = sa[mi][0][r]*sc, v1 = sa[mi][1][r]*sc, v2 = sa[mi][2][r]*sc,
                  v3 = sa[mi][3][r]*sc, v4 = sa[mi][4][r]*sc;
            bool ok4 = l15 < 13;             // col 64+l15 < 77
            float mx = fmaxf(fmaxf(v0, v1), fmaxf(v2, v3));
            if (ok4) mx = fmaxf(mx, v4);
#pragma unroll
            for (int off = 1; off < 16; off <<= 1) mx = fmaxf(mx, __shfl_xor(mx, off, 16));
            float p0 = __expf(v0-mx), p1 = __expf(v1-mx), p2 = __expf(v2-mx), p3 = __expf(v3-mx);
            float p4 = ok4 ? __expf(v4-mx) : 0.f;
            float sm = p0+p1+p2+p3+p4;
#pragma unroll
            for (int off = 1; off < 16; off <<= 1) sm += __shfl_xor(sm, off, 16);
            float inv = 1.f / sm;
            int row = mi*16 + lhi*4 + r;
            lds[qoff + row*88 + 0*16 + l15] = f2h(p0*inv);
            lds[qoff + row*88 + 1*16 + l15] = f2h(p1*inv);
            lds[qoff + row*88 + 2*16 + l15] = f2h(p2*inv);
            lds[qoff + row*88 + 3*16 + l15] = f2h(p3*inv);
            lds[qoff + row*88 + 4*16 + l15] = f2h(p4*inv);
        }
    __builtin_amdgcn_sched_barrier(0);

    // ---- O = P V (V^T frags from L2; Vt cols 77..95 are true zeros) ----
    f32x4 oa[2][5] = {};
    {
        f16x8 bv[15];
        const ushort* Vbase = Vt_g + (size_t)(b*8 + w) * 7680;
#pragma unroll
        for (int ni = 0; ni < 5; ++ni)
#pragma unroll
            for (int kk = 0; kk < 3; ++kk)
                bv[ni*3+kk] = *(const f16x8*)(Vbase + (size_t)(ni*16 + l15)*96 + kk*32 + lhi*8);
#pragma unroll
        for (int kk = 0; kk < 3; ++kk) {
            f16x8 ap[2];
            const int kcol = (kk < 2) ? (kk*32 + lhi*8) : (64 + (lhi & 1)*8);
#pragma unroll
            for (int mi = 0; mi < 2; ++mi) {
                ap[mi] = *(const f16x8*)&lds[qoff + (mi*16 + l15)*88 + kcol];
                if (kk == 2 && lhi >= 2) ap[mi] = zf;   // phantom s=80..95
            }
            PRIO1();
#pragma unroll
            for (int mi = 0; mi < 2; ++mi)
#pragma unroll
                for (int ni = 0; ni < 5; ++ni)
                    oa[mi][ni] = __builtin_amdgcn_mfma_f32_16x16x32_f16(ap[mi], bv[ni*3+kk], oa[mi][ni], 0, 0, 0);
            PRIO0();
        }
    }
    __syncthreads();   // all waves done with Q/P regions before ctxall overwrites

    // ---- ctxall[32][640], 16B-slot XOR swizzle, = concat of heads ----
#pragma unroll
    for (int mi = 0; mi < 2; ++mi)
#pragma unroll
        for (int ni = 0; ni < 5; ++ni)
#pragma unroll
            for (int r = 0; r < 4; ++r) {
                int row = mi*16 + lhi*4 + r;
                int col = w*80 + ni*16 + l15;
                int slot = col >> 3;
                int phys = (((slot & ~7) | ((slot ^ row) & 7)) << 3) | (col & 7);
                lds[row*640 + phys] = f2h(oa[mi][ni][r]);
            }
    __syncthreads();

    // ---- O projection: out = ctxall @ Wo[:, w*80..+80] + bo ----
    f32x4 cacc[2][5] = {};
    const ushort* Orow = WoT + (size_t)(w * 80) * 640;
#pragma unroll
    for (int ni = 0; ni < 5; ++ni)
#pragma unroll
        for (int kk = 0; kk < 2; ++kk)
            BbE[ni*2+kk] = *(const f16x8*)(Orow + (size_t)(ni*16 + l15)*640 + kk*32 + lhi*8);
#define OSTEP(BCUR, BNXT, KT) do { \
    const int kt_ = (KT); \
    if (kt_ < 9) { \
        _Pragma("unroll") for (int ni = 0; ni < 5; ++ni) \
        _Pragma("unroll") for (int kk = 0; kk < 2; ++kk) \
            (BNXT)[ni*2+kk] = *(const f16x8*)(Orow + (size_t)(ni*16+l15)*640 + (kt_+1)*64 + kk*32 + lhi*8); \
    } \
    _Pragma("unroll") for (int kk = 0; kk < 2; ++kk) { \
        f16x8 af[2]; \
        _Pragma("unroll") for (int mi = 0; mi < 2; ++mi) { \
            int row_ = mi*16 + l15; \
            af[mi] = *(const f16x8*)&lds[row_*640 + ((kt_*8 + ((kk*4 + lhi) ^ (row_ & 7))))*8]; \
        } \
        PRIO1(); \
        _Pragma("unroll") for (int mi = 0; mi < 2; ++mi) \
        _Pragma("unroll") for (int ni = 0; ni < 5; ++ni) \
            cacc[mi][ni] = __builtin_amdgcn_mfma_f32_16x16x32_f16(af[mi], (BCUR)[ni*2+kk], cacc[mi][ni], 0, 0, 0); \
        PRIO0(); \
    } \
} while (0)
    for (int kp = 0; kp < 5; ++kp) {
        OSTEP(BbE, BbO, 2*kp);
        OSTEP(BbO, BbE, 2*kp + 1);
    }
#undef OSTEP

    // ---- epilogue: f32 out + bias ----
#pragma unroll
    for (int ni = 0; ni < 5; ++ni) {
        int col = w*80 + ni*16 + l15;
        float bvl = bo[col];
#pragma unroll
        for (int mi = 0; mi < 2; ++mi)
#pragma unroll
            for (int r = 0; r < 4; ++r)
                out[(rowbase + mi*16 + lhi*4 + r) * 640 + col] = cacc[mi][ni][r] + bvl;
    }
}

extern "C" void kernel_launch(void* const* d_in, const int* in_sizes, int n_in,
                              void* d_out, int out_size, void* d_ws, size_t ws_size,
                              hipStream_t stream) {
    (void)in_sizes; (void)n_in; (void)out_size; (void)ws_size;
    const float* tokens  = (const float*)d_in[0];
    const float* context = (const float*)d_in[1];
    const float* Wq = (const float*)d_in[2];
    const float* Wk = (const float*)d_in[3];
    const float* Wv = (const float*)d_in[4];
    const float* Wo = (const float*)d_in[5];
    const float* bo = (const float*)d_in[6];
    float* out = (float*)d_out;

    ushort* ws   = (ushort*)d_ws;
    ushort* ctx16 = ws;                                   // 616*768
    ushort* WqT  = ctx16 + (size_t)616 * 768;             // 640*640
    ushort* WoT  = WqT  + (size_t)640 * 640;              // 640*640
    ushort* WkvT = WoT  + (size_t)640 * 640;              // 1280*768
    ushort* KVb  = WkvT + (size_t)1280 * 768;             // 616*1280
    ushort* Vt_g = KVb  + (size_t)616 * 1280;             // 64*80*96

    cvt_kernel<<<462, 256, 0, stream>>>(context, ctx16, 616 * 768 / 4);
    transpose_cvt4<<<dim3(20, 24, 4), dim3(32, 8), 0, stream>>>(Wq, Wo, Wk, Wv, WqT, WoT, WkvT);
    gemm_bt<1, 0><<<dim3(5, 10), 256, 0, stream>>>(ctx16, WkvT, KVb, nullptr, 616, 1280, 768);
    vtrans_kernel<<<64, 256, 0, stream>>>(KVb, Vt_g);
    fused_attn<<<dim3(128, 8), 512, 0, stream>>>(tokens, WqT, KVb, Vt_g, WoT, bo, out);
}

// Round 8
// 117.367 us; speedup vs baseline: 2.7120x; 2.2158x over previous
//
#include <hip/hip_runtime.h>
#include <hip/hip_bf16.h>
#include <hip/hip_fp16.h>

typedef __attribute__((ext_vector_type(4))) float f32x4;
typedef __attribute__((ext_vector_type(8))) _Float16 f16x8;
typedef __attribute__((ext_vector_type(8))) unsigned short u16x8;

__device__ __forceinline__ unsigned short f2h(float f) {
    _Float16 h = (_Float16)f;
    return __builtin_bit_cast(unsigned short, h);
}

#define GLOAD_LDS16(gp, lp) __builtin_amdgcn_global_load_lds( \
    (const __attribute__((address_space(1))) void*)(gp), \
    (__attribute__((address_space(3))) void*)(lp), 16, 0, 0)
#define PRIO1() __builtin_amdgcn_s_setprio(1)
#define PRIO0() __builtin_amdgcn_s_setprio(0)

// ---------------- fp32 -> fp16 elementwise convert (vectorized) ----------------
__global__ void cvt_kernel(const float* __restrict__ in, ushort* __restrict__ out, int n4) {
    int stride = gridDim.x * blockDim.x;
    for (int i = blockIdx.x * blockDim.x + threadIdx.x; i < n4; i += stride) {
        float4 v = ((const float4*)in)[i];
        ushort4 o;
        o.x = f2h(v.x); o.y = f2h(v.y); o.z = f2h(v.z); o.w = f2h(v.w);
        ((ushort4*)out)[i] = o;
    }
}

// ---------------- transpose + convert Wk/Wv (for the KV projection GEMM) ----------------
__global__ void transpose_cvt2(const float* __restrict__ Wk, const float* __restrict__ Wv,
                               ushort* __restrict__ WkvT) {
    __shared__ float tile[32][33];
    const int z = blockIdx.z;
    const float* src = z ? Wv : Wk;
    ushort* dst = WkvT + (size_t)z * 640 * 768;
    const int R = 768, C = 640;
    int tx = threadIdx.x, ty = threadIdx.y;
    int c = blockIdx.x * 32 + tx;
    int r0 = blockIdx.y * 32;
#pragma unroll
    for (int i = ty; i < 32; i += 8) {
        int r = r0 + i;
        tile[i][tx] = (r < R && c < C) ? src[(size_t)r * C + c] : 0.f;
    }
    __syncthreads();
    int rr = r0 + tx;
    int c0 = blockIdx.x * 32;
#pragma unroll
    for (int i = ty; i < 32; i += 8) {
        int cc = c0 + i;
        if (cc < C && rr < R) dst[(size_t)cc * R + rr] = f2h(tile[tx][i]);
    }
}

// ---------------- pack W (fp32 [640 k][640 n]) into fragment-linear f16 ----------------
// WF frag g = ((h*10 + kt)*10 + (ni*2+kk))*64 + lane, 8 elems:
//   elem e = f16( W[(kt*64 + kk*32 + (lane>>4)*8 + e)*640 + h*80 + ni*16 + (lane&15)] )
// In-kernel load: 64 lanes x 16B contiguous per fragment -> perfectly coalesced.
__global__ void pack_wfrag(const float* __restrict__ W, ushort* __restrict__ WF) {
    int g = blockIdx.x * 256 + threadIdx.x;   // 0 .. 51199
    if (g >= 51200) return;
    int lane = g & 63;
    int fi = (g >> 6) % 10;
    int kt = ((g >> 6) / 10) % 10;
    int h  = (g >> 6) / 100;
    int ni = fi >> 1, kk = fi & 1;
    int n  = h * 80 + ni * 16 + (lane & 15);
    int k0 = kt * 64 + kk * 32 + (lane >> 4) * 8;
    u16x8 o;
#pragma unroll
    for (int e = 0; e < 8; ++e) o[e] = f2h(W[(size_t)(k0 + e) * 640 + n]);
    *(u16x8*)&WF[(size_t)g * 8] = o;
}

// ---------------- pack K,V fragments from KVb ----------------
// frag g = ((b*8+h)*15 + (ni*3+kk))*64 + lane
// K: elem e = KVb[(b*77 + clamp(ni*16+l15,76))*1280 + h*80 + kk*32 + lhi*8 + e]
// V: elem e = (s=kk*32+lhi*8+e) < 77 ? KVb[(b*77+s)*1280 + 640 + h*80 + ni*16+l15] : 0
__global__ void pack_kvfrag(const ushort* __restrict__ KVb,
                            ushort* __restrict__ KF, ushort* __restrict__ VF) {
    int g = blockIdx.x * 256 + threadIdx.x;   // 0 .. 61439
    if (g >= 61440) return;
    int lane = g & 63;
    int fi = (g >> 6) % 15;
    int bh = (g >> 6) / 15;
    int b = bh >> 3, h = bh & 7;
    int ni = fi / 3, kk = fi % 3;
    int l15 = lane & 15, lhi = lane >> 4;
    int sr = ni * 16 + l15; if (sr > 76) sr = 76;
    int d0 = kk * 32 + lhi * 8;
    u16x8 ko, vo;
#pragma unroll
    for (int e = 0; e < 8; ++e)
        ko[e] = KVb[((size_t)b * 77 + sr) * 1280 + h * 80 + d0 + e];
    int dv = ni * 16 + l15;            // < 80 always
    int s0 = kk * 32 + lhi * 8;
#pragma unroll
    for (int e = 0; e < 8; ++e) {
        int s = s0 + e;
        vo[e] = (s < 77) ? KVb[((size_t)b * 77 + s) * 1280 + 640 + h * 80 + dv] : (ushort)0;
    }
    *(u16x8*)&KF[(size_t)g * 8] = ko;
    *(u16x8*)&VF[(size_t)g * 8] = vo;
}

// ---------------- 128x128 GEMM (for the tiny KV projection) ----------------
template<int OUT_F16, int HAS_BIAS>
__global__ __launch_bounds__(256) void gemm_bt(
    const ushort* __restrict__ A, const ushort* __restrict__ Bt,
    void* __restrict__ C, const float* __restrict__ bias,
    int M, int N, int K)
{
    __shared__ ushort As[128 * 64];
    __shared__ ushort Bs[128 * 64];
    const int tid = threadIdx.x;
    const int lane = tid & 63;
    const int w = tid >> 6;
    const int wr = (w >> 1) * 64, wc = (w & 1) * 64;
    const int m0 = blockIdx.x * 128, n0 = blockIdx.y * 128;
    const int l15 = lane & 15, lhi = lane >> 4;

    f32x4 acc[4][4] = {};

    for (int k0 = 0; k0 < K; k0 += 64) {
        __syncthreads();
#pragma unroll
        for (int i = 0; i < 4; ++i) {
            int c = i * 256 + tid;
            int m = m0 + (c >> 3);
            if (m > M - 1) m = M - 1;
            GLOAD_LDS16(A + (size_t)m * K + k0 + (c & 7) * 8, &As[c * 8]);
        }
#pragma unroll
        for (int i = 0; i < 4; ++i) {
            int c = i * 256 + tid;
            GLOAD_LDS16(Bt + (size_t)(n0 + (c >> 3)) * K + k0 + (c & 7) * 8, &Bs[c * 8]);
        }
        __syncthreads();
#pragma unroll
        for (int kk = 0; kk < 2; ++kk) {
            f16x8 af[4], bfr[4];
#pragma unroll
            for (int mi = 0; mi < 4; ++mi)
                af[mi] = *(const f16x8*)&As[(wr + mi * 16 + l15) * 64 + kk * 32 + lhi * 8];
#pragma unroll
            for (int ni = 0; ni < 4; ++ni)
                bfr[ni] = *(const f16x8*)&Bs[(wc + ni * 16 + l15) * 64 + kk * 32 + lhi * 8];
#pragma unroll
            for (int mi = 0; mi < 4; ++mi)
#pragma unroll
                for (int ni = 0; ni < 4; ++ni)
                    acc[mi][ni] = __builtin_amdgcn_mfma_f32_16x16x32_f16(
                        af[mi], bfr[ni], acc[mi][ni], 0, 0, 0);
        }
    }

#pragma unroll
    for (int mi = 0; mi < 4; ++mi)
#pragma unroll
        for (int ni = 0; ni < 4; ++ni)
#pragma unroll
            for (int r = 0; r < 4; ++r) {
                int row = m0 + wr + mi * 16 + lhi * 4 + r;
                int col = n0 + wc + ni * 16 + l15;
                if (row < M) {
                    float v = acc[mi][ni][r];
                    if (HAS_BIAS) v += bias[col];
                    if (OUT_F16) ((ushort*)C)[(size_t)row * N + col] = f2h(v);
                    else         ((float*)C)[(size_t)row * N + col] = v;
                }
            }
}

// ================= fused: tokens->Q-proj->attention->O-proj->out =================
// grid (64 tt, 8 b), 512 threads = 8 waves; wave w handles head w; 64 T-rows/block.
// IDENTICAL structure to the 151us R5 kernel; ONLY change: all W/K/V fragment loads
// now come from fragment-linear packed buffers (64 lanes x 16B contiguous per load)
// instead of 1280B-lane-stride gathers (R7 showed gathers dominate: dur scaled with
// block count at constant gather work, ~40 cache lines per load instruction).
// LDS 80 KiB: token dbuf [64][64] swz @0/4096; Q/P per-wave [64][80] @ w*5120;
//             ctxall [64][640] 16B-slot XOR swz @0 (aliases).
// __launch_bounds__ 2nd arg = blocks/CU semantics here; (512,2) -> 128 VGPR cap, clean.
__global__ __launch_bounds__(512, 2) void fused_attn(
    const float* __restrict__ tokens, const ushort* __restrict__ WqF,
    const ushort* __restrict__ KF, const ushort* __restrict__ VF,
    const ushort* __restrict__ WoF, const float* __restrict__ bo,
    float* __restrict__ out)
{
    __shared__ __align__(16) ushort lds[40960];   // 80 KiB
    const int tid = threadIdx.x;
    const int lane = tid & 63;
    const int w = tid >> 6;
    const int l15 = lane & 15, lhi = lane >> 4;
    const int tt = blockIdx.x, b = blockIdx.y;
    const size_t rowbase = (size_t)b * 4096 + (size_t)tt * 64;

    // staging indices: each thread stages one 8-f32 group per 64x64 chunk
    const int srow = tid >> 3;            // 0..63
    const int sc8  = tid & 7;             // slot 0..7
    const int sphys = sc8 ^ (srow & 7);   // swizzled slot

    // fragment-linear bases (ushort units; one frag = 512 ushorts = 64 lanes x 8)
    const ushort* WqFb = WqF + (size_t)w * 10 * 5120;   // + kt*5120 + f*512 + lane*8
    const ushort* WoFb = WoF + (size_t)w * 10 * 5120;
    const ushort* KFb  = KF + (size_t)(b * 8 + w) * 15 * 512;
    const ushort* VFb  = VF + (size_t)(b * 8 + w) * 15 * 512;

    // ---- prologue: stage tokens chunk 0 into bufA ----
    {
        const float4* sp = (const float4*)(tokens + (rowbase + srow) * 640 + sc8 * 8);
        float4 v0 = sp[0], v1 = sp[1];
        u16x8 o;
        o[0]=f2h(v0.x); o[1]=f2h(v0.y); o[2]=f2h(v0.z); o[3]=f2h(v0.w);
        o[4]=f2h(v1.x); o[5]=f2h(v1.y); o[6]=f2h(v1.z); o[7]=f2h(v1.w);
        *(u16x8*)&lds[srow * 64 + sphys * 8] = o;
    }
    f16x8 BbE[10], BbO[10];
#pragma unroll
    for (int f = 0; f < 10; ++f)
        BbE[f] = *(const f16x8*)(WqFb + f * 512 + lane * 8);
    __syncthreads();

    // ---- Q projection: qacc[4][5] = tokens_tile(64x640) @ Wq[:, w*80..+80] ----
    f32x4 qacc[4][5] = {};
#define QSTEP(BCUR, BNXT, KT, CURB, NXTB) do { \
    float4 s0_, s1_; \
    const int kt_ = (KT); \
    if (kt_ < 9) { \
        const float4* sp_ = (const float4*)(tokens + (rowbase + srow) * 640 + (kt_+1)*64 + sc8*8); \
        s0_ = sp_[0]; s1_ = sp_[1]; \
        _Pragma("unroll") for (int f = 0; f < 10; ++f) \
            (BNXT)[f] = *(const f16x8*)(WqFb + (size_t)(kt_+1)*5120 + f*512 + lane*8); \
    } \
    _Pragma("unroll") for (int kk = 0; kk < 2; ++kk) { \
        f16x8 af[4]; \
        _Pragma("unroll") for (int mi = 0; mi < 4; ++mi) { \
            int row_ = mi*16 + l15; \
            af[mi] = *(const f16x8*)&lds[(CURB) + row_*64 + (((kk*4 + lhi) ^ (row_ & 7)))*8]; \
        } \
        PRIO1(); \
        _Pragma("unroll") for (int mi = 0; mi < 4; ++mi) \
        _Pragma("unroll") for (int ni = 0; ni < 5; ++ni) \
            qacc[mi][ni] = __builtin_amdgcn_mfma_f32_16x16x32_f16(af[mi], (BCUR)[ni*2+kk], qacc[mi][ni], 0, 0, 0); \
        PRIO0(); \
    } \
    if (kt_ < 9) { \
        u16x8 o_; \
        o_[0]=f2h(s0_.x); o_[1]=f2h(s0_.y); o_[2]=f2h(s0_.z); o_[3]=f2h(s0_.w); \
        o_[4]=f2h(s1_.x); o_[5]=f2h(s1_.y); o_[6]=f2h(s1_.z); o_[7]=f2h(s1_.w); \
        *(u16x8*)&lds[(NXTB) + srow*64 + sphys*8] = o_; \
    } \
    __syncthreads(); \
} while (0)

    for (int kp = 0; kp < 5; ++kp) {
        QSTEP(BbE, BbO, 2*kp,     0,    4096);
        QSTEP(BbO, BbE, 2*kp + 1, 4096, 0);
    }
#undef QSTEP

    // ---- write Q f16 into per-wave [64][80] region (aliases token bufs, now dead) ----
    const int qoff = w * 5120;
#pragma unroll
    for (int mi = 0; mi < 4; ++mi)
#pragma unroll
        for (int ni = 0; ni < 5; ++ni)
#pragma unroll
            for (int r = 0; r < 4; ++r)
                lds[qoff + (mi*16 + lhi*4 + r)*80 + ni*16 + l15] = f2h(qacc[mi][ni][r]);
    __builtin_amdgcn_sched_barrier(0);

    const f16x8 zf = {};
    // ---- S = Q K^T (K frags from packed KF, coalesced) ----
    f32x4 sa[4][5] = {};
    {
        f16x8 bk[15];
#pragma unroll
        for (int f = 0; f < 15; ++f)
            bk[f] = *(const f16x8*)(KFb + f * 512 + lane * 8);
#pragma unroll
        for (int kk = 0; kk < 3; ++kk) {
            f16x8 aq[4];
            const int kcol = (kk < 2) ? (kk*32 + lhi*8) : (64 + (lhi & 1)*8);
#pragma unroll
            for (int mi = 0; mi < 4; ++mi) {
                aq[mi] = *(const f16x8*)&lds[qoff + (mi*16 + l15)*80 + kcol];
                if (kk == 2 && lhi >= 2) aq[mi] = zf;   // phantom k-slots d=80..95
            }
            PRIO1();
#pragma unroll
            for (int mi = 0; mi < 4; ++mi)
#pragma unroll
                for (int ni = 0; ni < 5; ++ni)
                    sa[mi][ni] = __builtin_amdgcn_mfma_f32_16x16x32_f16(aq[mi], bk[ni*3+kk], sa[mi][ni], 0, 0, 0);
            PRIO0();
        }
    }
    __builtin_amdgcn_sched_barrier(0);

    // ---- softmax over s (77 valid), store P f16 into the same per-wave region ----
    const float sc = 0.11180339887498949f;   // 1/sqrt(80)
#pragma unroll
    for (int mi = 0; mi < 4; ++mi)
#pragma unroll
        for (int r = 0; r < 4; ++r) {
            float v0 = sa[mi][0][r]*sc, v1 = sa[mi][1][r]*sc, v2 = sa[mi][2][r]*sc,
                  v3 = sa[mi][3][r]*sc, v4 = sa[mi][4][r]*sc;
            bool ok4 = l15 < 13;             // col 64+l15 < 77
            float mx = fmaxf(fmaxf(v0, v1), fmaxf(v2, v3));
            if (ok4) mx = fmaxf(mx, v4);
#pragma unroll
            for (int off = 1; off < 16; off <<= 1) mx = fmaxf(mx, __shfl_xor(mx, off, 16));
            float p0 = __expf(v0-mx), p1 = __expf(v1-mx), p2 = __expf(v2-mx), p3 = __expf(v3-mx);
            float p4 = ok4 ? __expf(v4-mx) : 0.f;
            float sm = p0+p1+p2+p3+p4;
#pragma unroll
            for (int off = 1; off < 16; off <<= 1) sm += __shfl_xor(sm, off, 16);
            float inv = 1.f / sm;
            int row = mi*16 + lhi*4 + r;
            lds[qoff + row*80 + 0*16 + l15] = f2h(p0*inv);
            lds[qoff + row*80 + 1*16 + l15] = f2h(p1*inv);
            lds[qoff + row*80 + 2*16 + l15] = f2h(p2*inv);
            lds[qoff + row*80 + 3*16 + l15] = f2h(p3*inv);
            lds[qoff + row*80 + 4*16 + l15] = f2h(p4*inv);
        }
    __builtin_amdgcn_sched_barrier(0);

    // ---- O = P V (V frags from packed VF, coalesced; cols >=77 true zeros) ----
    f32x4 oa[4][5] = {};
    {
        f16x8 bv[15];
#pragma unroll
        for (int f = 0; f < 15; ++f)
            bv[f] = *(const f16x8*)(VFb + f * 512 + lane * 8);
#pragma unroll
        for (int kk = 0; kk < 3; ++kk) {
            f16x8 ap[4];
            const int kcol = (kk < 2) ? (kk*32 + lhi*8) : (64 + (lhi & 1)*8);
#pragma unroll
            for (int mi = 0; mi < 4; ++mi) {
                ap[mi] = *(const f16x8*)&lds[qoff + (mi*16 + l15)*80 + kcol];
                if (kk == 2 && lhi >= 2) ap[mi] = zf;   // phantom s=80..95
            }
            PRIO1();
#pragma unroll
            for (int mi = 0; mi < 4; ++mi)
#pragma unroll
                for (int ni = 0; ni < 5; ++ni)
                    oa[mi][ni] = __builtin_amdgcn_mfma_f32_16x16x32_f16(ap[mi], bv[ni*3+kk], oa[mi][ni], 0, 0, 0);
            PRIO0();
        }
    }
    __syncthreads();   // all waves done with Q/P regions before ctxall overwrites

    // ---- ctxall[64][640], 16B-slot XOR swizzle, = concat of heads ----
#pragma unroll
    for (int mi = 0; mi < 4; ++mi)
#pragma unroll
        for (int ni = 0; ni < 5; ++ni)
#pragma unroll
            for (int r = 0; r < 4; ++r) {
                int row = mi*16 + lhi*4 + r;
                int col = w*80 + ni*16 + l15;
                int slot = col >> 3;
                int phys = (((slot & ~7) | ((slot ^ row) & 7)) << 3) | (col & 7);
                lds[row*640 + phys] = f2h(oa[mi][ni][r]);
            }
    __syncthreads();

    // ---- O projection: out = ctxall @ Wo[:, w*80..+80] + bo ----
    f32x4 cacc[4][5] = {};
#pragma unroll
    for (int f = 0; f < 10; ++f)
        BbE[f] = *(const f16x8*)(WoFb + f * 512 + lane * 8);
#define OSTEP(BCUR, BNXT, KT) do { \
    const int kt_ = (KT); \
    if (kt_ < 9) { \
        _Pragma("unroll") for (int f = 0; f < 10; ++f) \
            (BNXT)[f] = *(const f16x8*)(WoFb + (size_t)(kt_+1)*5120 + f*512 + lane*8); \
    } \
    _Pragma("unroll") for (int kk = 0; kk < 2; ++kk) { \
        f16x8 af[4]; \
        _Pragma("unroll") for (int mi = 0; mi < 4; ++mi) { \
            int row_ = mi*16 + l15; \
            af[mi] = *(const f16x8*)&lds[row_*640 + ((kt_*8 + ((kk*4 + lhi) ^ (row_ & 7))))*8]; \
        } \
        PRIO1(); \
        _Pragma("unroll") for (int mi = 0; mi < 4; ++mi) \
        _Pragma("unroll") for (int ni = 0; ni < 5; ++ni) \
            cacc[mi][ni] = __builtin_amdgcn_mfma_f32_16x16x32_f16(af[mi], (BCUR)[ni*2+kk], cacc[mi][ni], 0, 0, 0); \
        PRIO0(); \
    } \
} while (0)
    for (int kp = 0; kp < 5; ++kp) {
        OSTEP(BbE, BbO, 2*kp);
        OSTEP(BbO, BbE, 2*kp + 1);
    }
#undef OSTEP

    // ---- epilogue: f32 out + bias ----
#pragma unroll
    for (int ni = 0; ni < 5; ++ni) {
        int col = w*80 + ni*16 + l15;
        float bvl = bo[col];
#pragma unroll
        for (int mi = 0; mi < 4; ++mi)
#pragma unroll
            for (int r = 0; r < 4; ++r)
                out[(rowbase + mi*16 + lhi*4 + r) * 640 + col] = cacc[mi][ni][r] + bvl;
    }
}

extern "C" void kernel_launch(void* const* d_in, const int* in_sizes, int n_in,
                              void* d_out, int out_size, void* d_ws, size_t ws_size,
                              hipStream_t stream) {
    (void)in_sizes; (void)n_in; (void)out_size; (void)ws_size;
    const float* tokens  = (const float*)d_in[0];
    const float* context = (const float*)d_in[1];
    const float* Wq = (const float*)d_in[2];
    const float* Wk = (const float*)d_in[3];
    const float* Wv = (const float*)d_in[4];
    const float* Wo = (const float*)d_in[5];
    const float* bo = (const float*)d_in[6];
    float* out = (float*)d_out;

    ushort* ws   = (ushort*)d_ws;
    ushort* ctx16 = ws;                                   // 616*768
    ushort* WkvT = ctx16 + (size_t)616 * 768;             // 1280*768
    ushort* KVb  = WkvT + (size_t)1280 * 768;             // 616*1280
    ushort* WqF  = KVb  + (size_t)616 * 1280;             // 51200*8 = 640*640
    ushort* WoF  = WqF  + (size_t)640 * 640;              // 640*640
    ushort* KF   = WoF  + (size_t)640 * 640;              // 61440*8
    ushort* VF   = KF   + (size_t)61440 * 8;              // 61440*8

    cvt_kernel<<<462, 256, 0, stream>>>(context, ctx16, 616 * 768 / 4);
    transpose_cvt2<<<dim3(20, 24, 2), dim3(32, 8), 0, stream>>>(Wk, Wv, WkvT);
    pack_wfrag<<<200, 256, 0, stream>>>(Wq, WqF);
    pack_wfrag<<<200, 256, 0, stream>>>(Wo, WoF);
    gemm_bt<1, 0><<<dim3(5, 10), 256, 0, stream>>>(ctx16, WkvT, KVb, nullptr, 616, 1280, 768);
    pack_kvfrag<<<240, 256, 0, stream>>>(KVb, KF, VF);
    fused_attn<<<dim3(64, 8), 512, 0, stream>>>(tokens, WqF, KF, VF, WoF, bo, out);
}